// Round 13
// baseline (213.353 us; speedup 1.0000x reference)
//
#include <hip/hip_runtime.h>
#include <hip/hip_bf16.h>
#include <stdint.h>

#define BB 2
#define SS 4096
#define WW 512
#define DD 64
#define HH 8
// 0.125 (1/sqrt(D)) * log2(e): scores come out in log2 domain -> exp2 softmax
#define QSCALE 0.1803368801111244f

typedef __hip_bfloat16 bf16;
typedef __bf16 bf16x8 __attribute__((ext_vector_type(8)));
typedef float f32x16 __attribute__((ext_vector_type(16)));
typedef unsigned int u32x4 __attribute__((ext_vector_type(4)));
typedef unsigned int u32x2 __attribute__((ext_vector_type(2)));

union U4 { u32x4 u4; unsigned int u[4]; bf16x8 v; };

__device__ __forceinline__ float ldv(const float* p, size_t i) { return p[i]; }
__device__ __forceinline__ float ldv(const bf16* p, size_t i)  { return __bfloat162float(p[i]); }

__device__ __forceinline__ unsigned short f2bu(float f) {
    union Ub { bf16 b; unsigned short u; } t;
    t.b = __float2bfloat16(f);
    return t.u;
}

__device__ __forceinline__ float fast_exp2(float x) {
#if __has_builtin(__builtin_amdgcn_exp2f)
    return __builtin_amdgcn_exp2f(x);   // raw v_exp_f32 (1 ULP); args bounded
#else
    return exp2f(x);
#endif
}

__device__ __forceinline__ f32x16 mfma_bf16(bf16x8 a, bf16x8 b, f32x16 c) {
    return __builtin_amdgcn_mfma_f32_32x32x16_bf16(a, b, c, 0, 0, 0);
}

// pack two fp32 -> bf16x2 word (round-half-up via +0x8000; v_perm grabs hi16s)
__device__ __forceinline__ unsigned int pk_bf16(float lo, float hi) {
    unsigned int a = __float_as_uint(lo) + 0x8000u;
    unsigned int b = __float_as_uint(hi) + 0x8000u;
    return __builtin_amdgcn_perm(b, a, 0x07060302u);
}

// Per-block dtype detection (round-2 evidence: fp32; keep for safety).
__device__ __forceinline__ int block_detect(const void* raw, int* cntLds)
{
    if (threadIdx.x == 0) *cntLds = 0;
    __syncthreads();
    const bf16* xb = (const bf16*)raw;
    const float v = __bfloat162float(xb[2 * threadIdx.x]);
    const float a = fabsf(v);
    const bool insane = !(v == v) || (a >= 1.0e4f) || (a != 0.0f && a <= 1.0e-8f);
    const unsigned long long m = __ballot(insane);
    if ((threadIdx.x & 63) == 0) atomicAdd(cntLds, __popcll(m));
    __syncthreads();
    return (*cntLds * 2 > 256) ? 1 : 0;   // 1 => fp32 data
}

// typed staging registers: raw loads kept in native dtype so the prefetch
// distance survives; pack to bf16 only at LDS-write time.
template<typename T> struct StReg;
template<> struct StReg<bf16>  { u32x4 v; };
template<> struct StReg<float> { float4 a, b; };

__device__ __forceinline__ void stld(StReg<bf16>& r, const bf16* p, size_t i) {
    r.v = *(const u32x4*)((const unsigned short*)p + i);
}
__device__ __forceinline__ void stld(StReg<float>& r, const float* p, size_t i) {
    r.a = *(const float4*)(p + i);
    r.b = *(const float4*)(p + i + 4);
}
__device__ __forceinline__ u32x4 stpack(const StReg<bf16>& r) { return r.v; }
__device__ __forceinline__ u32x4 stpack(const StReg<float>& r) {
    u32x4 w;
    w[0] = pk_bf16(r.a.x, r.a.y); w[1] = pk_bf16(r.a.z, r.a.w);
    w[2] = pk_bf16(r.b.x, r.b.y); w[3] = pk_bf16(r.b.z, r.b.w);
    return w;
}

// ---------------------------------------------------------------------------
// wprep: weights -> packed col-major Wb[c][w], c = [K 64 | V 64 | Q 8x64 | P 64],
// QSCALE folded into Q cols; biases bb[704]; block 0 publishes x-dtype flag.
// Grid 88 = 11 c-groups x 8 w-groups.
// ---------------------------------------------------------------------------
template<typename T>
__device__ __forceinline__ void prep_w_body(
    const T* Wq, const T* bq, const T* Wk, const T* bk,
    const T* Wv, const T* bv, const T* Wp, const T* bp,
    unsigned short* Wb, float* bb, float (*Tt)[65], int pwblk)
{
    const int tid = threadIdx.x;
    const int cg = pwblk >> 3, wg = pwblk & 7;
    const int c0 = cg * 64, w0 = wg * 64;
    const T* src = (cg == 0) ? Wk : (cg == 1) ? Wv
                 : (cg == 10) ? Wp : (Wq + (size_t)(cg - 2) * WW * DD);
    const float scale = (cg >= 2 && cg < 10) ? QSCALE : 1.0f;

    #pragma unroll
    for (int i = 0; i < 16; ++i) {
        const int e = i * 256 + tid, w = e >> 6, d = e & 63;
        Tt[w][d] = ldv(src, (size_t)(w0 + w) * DD + d) * scale;
    }
    __syncthreads();
    #pragma unroll
    for (int i = 0; i < 16; ++i) {
        const int e = i * 256 + tid, d = e >> 6, w = e & 63;
        Wb[(size_t)(c0 + d) * WW + w0 + w] = f2bu(Tt[w][d]);
    }
    if (pwblk == 0) {
        #pragma unroll
        for (int i = 0; i < 3; ++i) {
            const int c = tid + i * 256;
            if (c < 704) {
                float v;
                if (c < 64)       v = ldv(bk, c);
                else if (c < 128) v = ldv(bv, c - 64);
                else if (c < 640) v = ldv(bq, c - 128) * QSCALE;
                else              v = ldv(bp, c - 640);
                bb[c] = v;
            }
        }
    }
}

__global__ __launch_bounds__(256) void wprep_kernel(
    const void* x, const void* Wq, const void* bq, const void* Wk, const void* bk,
    const void* Wv, const void* bv, const void* Wp, const void* bp,
    unsigned short* Wb, float* bb, int* flag)
{
    __shared__ float Tt[64][65];
    __shared__ int cnt;
    if (blockIdx.x == 0) {
        const int flx = block_detect(x, &cnt);
        if (threadIdx.x == 0) *flag = flx;      // consumed by outp epilogue
    }
    const int fl = block_detect(Wk, &cnt);
    if (fl)
        prep_w_body<float>((const float*)Wq, (const float*)bq, (const float*)Wk,
                           (const float*)bk, (const float*)Wv, (const float*)bv,
                           (const float*)Wp, (const float*)bp, Wb, bb, Tt, blockIdx.x);
    else
        prep_w_body<bf16>((const bf16*)Wq, (const bf16*)bq, (const bf16*)Wk,
                          (const bf16*)bk, (const bf16*)Wv, (const bf16*)bv,
                          (const bf16*)Wp, (const bf16*)bp, Wb, bb, Tt, blockIdx.x);
}

// ---------------------------------------------------------------------------
// proj: C[8192x640] = x[8192x512] @ Wb^T + bb -> Kb, Qb, and (for nblk==0)
// V directly transposed+permuted to Vtg[b][d][s(t)] via an LDS bounce.
// x converted fp32->bf16 inline during A-staging (typed prefetch regs).
// ---------------------------------------------------------------------------
#define KP 40

template<typename T>
__device__ __forceinline__ void proj_body(
    const T* xsrc, const unsigned short* Wb, const float* bb,
    bf16* Kb, bf16* Qb, unsigned short* Vtg,
    unsigned short* As0, unsigned short* Bs0)
{
    const int tid = threadIdx.x;
    const int wv = tid >> 6, ln = tid & 63;
    const int g = ln >> 5, cc = ln & 31;
    const int nblk = blockIdx.x % 5, mblk = blockIdx.x / 5;
    const int row0 = mblk * 128, n0 = nblk * 128;
    const int wm = (wv & 1) * 64, wn = (wv >> 1) * 64;

    const int sm = tid >> 2;
    const int sko = (tid & 3) * 8;

    StReg<T> pa[2];
    u32x4 pb[2];
    #define GLOAD(kt)                                                          \
        do {                                                                   \
            _Pragma("unroll")                                                  \
            for (int i = 0; i < 2; ++i) {                                      \
                const int m = sm + i * 64;                                     \
                stld(pa[i], xsrc, (size_t)(row0 + m) * WW + (kt) * 32 + sko);  \
                pb[i] = *(const u32x4*)&Wb[(size_t)(n0 + m) * WW + (kt) * 32 + sko]; \
            }                                                                  \
        } while (0)
    #define LWRITE(buf)                                                        \
        do {                                                                   \
            _Pragma("unroll")                                                  \
            for (int i = 0; i < 2; ++i) {                                      \
                const int m = sm + i * 64;                                     \
                *(u32x4*)&As0[(buf) * (128 * KP) + m * KP + sko] = stpack(pa[i]); \
                *(u32x4*)&Bs0[(buf) * (128 * KP) + m * KP + sko] = pb[i];      \
            }                                                                  \
        } while (0)

    f32x16 acc[2][2];
    #pragma unroll
    for (int a = 0; a < 2; ++a)
        #pragma unroll
        for (int c2 = 0; c2 < 2; ++c2)
            #pragma unroll
            for (int i = 0; i < 16; ++i) acc[a][c2][i] = 0.f;

    GLOAD(0); LWRITE(0);
    GLOAD(1);

    for (int kt = 0; kt < 16; ++kt) {
        __syncthreads();
        const int buf = kt & 1;
        #pragma unroll
        for (int ks = 0; ks < 2; ++ks) {
            U4 af[2], bfr[2];
            #pragma unroll
            for (int ms = 0; ms < 2; ++ms)
                af[ms].u4 = *(const u32x4*)&As0[buf * (128 * KP) +
                                                (wm + ms * 32 + cc) * KP + ks * 16 + g * 8];
            #pragma unroll
            for (int ns = 0; ns < 2; ++ns)
                bfr[ns].u4 = *(const u32x4*)&Bs0[buf * (128 * KP) +
                                                 (wn + ns * 32 + cc) * KP + ks * 16 + g * 8];
            #pragma unroll
            for (int ms = 0; ms < 2; ++ms)
                #pragma unroll
                for (int ns = 0; ns < 2; ++ns)
                    acc[ms][ns] = mfma_bf16(af[ms].v, bfr[ns].v, acc[ms][ns]);
        }
        if (kt < 15) {
            LWRITE(buf ^ 1);
            if (kt < 14) GLOAD(kt + 2);
        }
    }
    #undef GLOAD
    #undef LWRITE

    const int b = row0 >> 12;
    #pragma unroll
    for (int ns = 0; ns < 2; ++ns) {
        const int c = n0 + wn + ns * 32 + cc;
        const int grp = c >> 6, d = c & 63;
        const float bias = bb[c];
        if (grp != 1) {   // V handled via LDS transpose below
            bf16* base = (grp == 0) ? Kb
                       : Qb + (size_t)((b * HH + grp - 2) - b) * SS * DD;
            #pragma unroll
            for (int ms = 0; ms < 2; ++ms) {
                #pragma unroll
                for (int reg = 0; reg < 16; ++reg) {
                    const int r = (reg & 3) + 8 * (reg >> 2) + 4 * g;
                    const int row = row0 + wm + ms * 32 + r;
                    base[(size_t)row * DD + d] = __float2bfloat16(acc[ms][ns][reg] + bias);
                }
            }
        }
    }

    // V epilogue: acc (waves 2,3 of nblk==0) -> LDS [t][d] -> permuted Vtg.
    __syncthreads();                       // all As/Bs reads done; reuse As
    unsigned short (*Vl)[65] = (unsigned short (*)[65])As0;   // 128x65 fits
    if (nblk == 0 && wv >= 2) {
        #pragma unroll
        for (int ns = 0; ns < 2; ++ns) {
            const int d = ns * 32 + cc;
            const float bias = bb[64 + d];
            #pragma unroll
            for (int ms = 0; ms < 2; ++ms)
                #pragma unroll
                for (int reg = 0; reg < 16; ++reg) {
                    const int r = wm + ms * 32 + (reg & 3) + 8 * (reg >> 2) + 4 * g;
                    Vl[r][d] = f2bu(acc[ms][ns][reg] + bias);
                }
        }
    }
    __syncthreads();
    if (nblk == 0) {
        const int t0 = row0 & 4095;
        const int d = tid >> 2, tch = tid & 3;
        unsigned short* op = Vtg + ((size_t)b * DD + d) * SS + t0 + tch * 32;
        unsigned short tmp[32];
        #pragma unroll
        for (int j = 0; j < 32; ++j) tmp[j] = Vl[tch * 32 + j][d];
        const int soff[8] = {0, 8, 4, 12, 16, 24, 20, 28};   // 4-groups under vperm
        #pragma unroll
        for (int jg = 0; jg < 8; ++jg) {
            u32x2 w2;
            w2[0] = (unsigned int)tmp[jg * 4 + 0] | ((unsigned int)tmp[jg * 4 + 1] << 16);
            w2[1] = (unsigned int)tmp[jg * 4 + 2] | ((unsigned int)tmp[jg * 4 + 3] << 16);
            *(u32x2*)&op[soff[jg]] = w2;
        }
    }
}

__global__ __launch_bounds__(256, 2) void proj_mfma_kernel(
    const void* x, const unsigned short* __restrict__ Wb,
    const float* __restrict__ bb,
    bf16* __restrict__ Kb, bf16* __restrict__ Qb, unsigned short* __restrict__ Vtg)
{
    __shared__ unsigned short As[2][128 * KP];
    __shared__ unsigned short Bs[2][128 * KP];
    __shared__ int cnt;
    const int fl = block_detect(x, &cnt);
    if (fl)
        proj_body<float>((const float*)x, Wb, bb, Kb, Qb, Vtg, &As[0][0], &Bs[0][0]);
    else
        proj_body<bf16>((const bf16*)x, Wb, bb, Kb, Qb, Vtg, &As[0][0], &Bs[0][0]);
}

// ---------------------------------------------------------------------------
// attn_mfma<TSPLIT>: flash attention, fixed-max softmax (m=0). Round-12
// structure (K+V both staged via double-buffered LDS, VTP=72, 0 conflicts).
// TSPLIT t-partials (exactly additive) to Zp/Lp fp32; combine normalizes.
// ---------------------------------------------------------------------------
#define VTP 72
#define ZP_PART ((size_t)16 * 64 * 4096)   // floats per partial Z
#define LP_PART ((size_t)16 * 4096)        // floats per partial l

template<int TSPLIT>
__global__ __launch_bounds__(256, 4) void attn_mfma_kernel(
    const bf16* __restrict__ Kb, const unsigned short* __restrict__ Vtg,
    const bf16* __restrict__ Qb, bf16* __restrict__ Zb,
    float* __restrict__ Zp, float* __restrict__ Lp)
{
    __shared__ unsigned short Vt[2][64 * VTP];
    __shared__ unsigned short Kt[2][64 * VTP];

    const int tid = threadIdx.x;
    const int wv = tid >> 6, ln = tid & 63;
    const int g  = ln >> 5, cc = ln & 31;
    const int chunk = blockIdx.x & 31;
    const int tsp = (TSPLIT == 1) ? 0 : ((blockIdx.x / 32) % TSPLIT);
    const int bh  = blockIdx.x / (32 * TSPLIT);
    const int b = bh >> 3, h = bh & 7;
    const int qw = chunk * 128 + wv * 32;      // wave's 32 q rows
    const int it0 = tsp * (64 / TSPLIT);
    const int itN = it0 + 64 / TSPLIT;

    const unsigned short* Kg = (const unsigned short*)(Kb + (size_t)b * SS * DD);
    const unsigned short* Vg = Vtg + (size_t)b * DD * SS;   // [d][s(t)]
    const char* Qg = (const char*)(Qb + (size_t)(b * HH + h) * SS * DD);

    const int sr = tid >> 2, sc = (tid & 3) * 16;
    const unsigned short* VgRow = Vg + (size_t)sr * SS;

    U4 qf[4];
    #pragma unroll
    for (int ks = 0; ks < 4; ++ks)
        qf[ks].u4 = *(const u32x4*)(Qg +
            (size_t)((qw + cc) * 64 + g * 8 + ks * 16) * 2);

    f32x16 zacc[2];
    #pragma unroll
    for (int dt = 0; dt < 2; ++dt)
        #pragma unroll
        for (int i = 0; i < 16; ++i) zacc[dt][i] = 0.f;

    float la = 0.f, lb2 = 0.f;

    {   // prologue: stage first K+V tiles into buf 0
        const unsigned short* ksrc = Kg + (size_t)(it0 * 64 + sr) * 64 + sc;
        const unsigned short* vsrc = VgRow + it0 * 64 + sc;
        *(u32x4*)&Kt[0][sr * VTP + sc + 0] = *(const u32x4*)&ksrc[0];
        *(u32x4*)&Kt[0][sr * VTP + sc + 8] = *(const u32x4*)&ksrc[8];
        *(u32x4*)&Vt[0][sr * VTP + sc + 0] = *(const u32x4*)&vsrc[0];
        *(u32x4*)&Vt[0][sr * VTP + sc + 8] = *(const u32x4*)&vsrc[8];
    }

    for (int it = it0; it < itN; ++it) {
        __syncthreads();
        const int buf = it & 1;
        const bool more = (it + 1) < itN;
        u32x4 pk0, pk1, pv0, pv1;
        if (more) {
            const unsigned short* ksrc = Kg + (size_t)((it + 1) * 64 + sr) * 64 + sc;
            const unsigned short* vsrc = VgRow + (it + 1) * 64 + sc;
            pk0 = *(const u32x4*)&ksrc[0];
            pk1 = *(const u32x4*)&ksrc[8];
            pv0 = *(const u32x4*)&vsrc[0];
            pv1 = *(const u32x4*)&vsrc[8];
        }

        #pragma unroll
        for (int si = 0; si < 2; ++si) {
            U4 kf[4];
            #pragma unroll
            for (int ks = 0; ks < 4; ++ks)
                kf[ks].u4 = *(const u32x4*)&Kt[buf][(si * 32 + cc) * VTP +
                                                    ks * 16 + g * 8];

            f32x16 s;
            #pragma unroll
            for (int i = 0; i < 16; ++i) s[i] = 0.f;
            #pragma unroll
            for (int ks = 0; ks < 4; ++ks) s = mfma_bf16(kf[ks].v, qf[ks].v, s);

            float p[16];
            #pragma unroll
            for (int i = 0; i < 16; ++i) p[i] = fast_exp2(s[i]);
            #pragma unroll
            for (int i = 0; i < 8; ++i) { la += p[i]; lb2 += p[8 + i]; }

            unsigned int w0[8];
            #pragma unroll
            for (int i2 = 0; i2 < 8; ++i2)
                w0[i2] = pk_bf16(p[2 * i2], p[2 * i2 + 1]);

            #pragma unroll
            for (int ks = 0; ks < 2; ++ks) {
                U4 pb;
                pb.u[0] = w0[ks * 4 + 0]; pb.u[1] = w0[ks * 4 + 1];
                pb.u[2] = w0[ks * 4 + 2]; pb.u[3] = w0[ks * 4 + 3];
                #pragma unroll
                for (int dt = 0; dt < 2; ++dt) {
                    U4 vf;
                    vf.u4 = *(const u32x4*)&Vt[buf][(dt * 32 + cc) * VTP +
                                                    si * 32 + ks * 16 + g * 8];
                    zacc[dt] = mfma_bf16(vf.v, pb.v, zacc[dt]);
                }
            }
        }

        if (more) {
            *(u32x4*)&Kt[buf ^ 1][sr * VTP + sc + 0] = pk0;
            *(u32x4*)&Kt[buf ^ 1][sr * VTP + sc + 8] = pk1;
            *(u32x4*)&Vt[buf ^ 1][sr * VTP + sc + 0] = pv0;
            *(u32x4*)&Vt[buf ^ 1][sr * VTP + sc + 8] = pv1;
        }
    }

    float l = la + lb2;
    l += __shfl_xor(l, 32, 64);

    if (TSPLIT == 1) {
        const float rr = 1.0f / l;
        bf16* zp = Zb + (size_t)(b * SS + qw + cc) * (HH * DD) + h * DD + g * 4;
        #pragma unroll
        for (int dt = 0; dt < 2; ++dt)
            #pragma unroll
            for (int i = 0; i < 16; ++i) {
                const int d = (i & 3) + 8 * (i >> 2) + 32 * dt;
                zp[d] = __float2bfloat16(zacc[dt][i] * rr);
            }
    } else {
        float* zp0 = Zp + (size_t)(tsp * 16 + bh) * (64 * 4096);
        #pragma unroll
        for (int dt = 0; dt < 2; ++dt)
            #pragma unroll
            for (int i = 0; i < 16; ++i) {
                const int d = (i & 3) + 8 * (i >> 2) + 4 * g + 32 * dt;
                zp0[(size_t)d * 4096 + qw + cc] = zacc[dt][i];
            }
        if (g == 0)
            Lp[(size_t)(tsp * 16 + bh) * 4096 + qw + cc] = l;
    }
}

// ---------------------------------------------------------------------------
// combine<PARTS>: Zb[b][s][h*64+d] = sum_p Zp_p[bh][d][s] / sum_p Lp_p[bh][s].
// ---------------------------------------------------------------------------
template<int PARTS>
__global__ __launch_bounds__(256) void combine_kernel(
    const float* __restrict__ Zp, const float* __restrict__ Lp,
    bf16* __restrict__ Zb)
{
    const size_t T = (size_t)blockIdx.x * 256 + threadIdx.x;
    const int sblk = (int)(T & 511);
    const int d  = (int)((T >> 9) & 63);
    const int bh = (int)(T >> 15);
    const int s0 = sblk * 8;
    const int b = bh >> 3, h = bh & 7;

    float z[8], lv[8];
    #pragma unroll
    for (int j = 0; j < 8; ++j) { z[j] = 0.f; lv[j] = 0.f; }

    #pragma unroll
    for (int pp = 0; pp < PARTS; ++pp) {
        const float* p0 = Zp + pp * ZP_PART + ((size_t)bh * 64 + d) * 4096 + s0;
        const float* l0 = Lp + pp * LP_PART + (size_t)bh * 4096 + s0;
        #pragma unroll
        for (int j = 0; j < 8; j += 4) {
            const float4 a = *(const float4*)(p0 + j);
            z[j] += a.x; z[j+1] += a.y; z[j+2] += a.z; z[j+3] += a.w;
            const float4 e = *(const float4*)(l0 + j);
            lv[j] += e.x; lv[j+1] += e.y; lv[j+2] += e.z; lv[j+3] += e.w;
        }
    }
    bf16* zo = Zb + ((size_t)(b * SS + s0)) * (HH * DD) + h * DD + d;
    #pragma unroll
    for (int j = 0; j < 8; ++j)
        zo[(size_t)j * (HH * DD)] = __float2bfloat16(z[j] / lv[j]);
}

// ---------------------------------------------------------------------------
// outp_mfma: out[8192x64] = Zc[8192x512] @ Wp + bp.
// ---------------------------------------------------------------------------
__global__ __launch_bounds__(256) void outp_mfma_kernel(
    const bf16* __restrict__ Zb, const unsigned short* __restrict__ Wb,
    const float* __restrict__ bb, const int* flag, void* out)
{
    __shared__ unsigned short As[2][128 * KP];
    __shared__ unsigned short Bs[2][64 * KP];

    const int tid = threadIdx.x;
    const int wv = tid >> 6, ln = tid & 63;
    const int g = ln >> 5, cc = ln & 31;
    const int row0 = blockIdx.x * 128;
    const int sm = tid >> 2, sko = (tid & 3) * 8;

    const unsigned short* Zu = (const unsigned short*)Zb;
    const unsigned short* Wn = Wb + (size_t)640 * WW;   // Wp section (64 cols)
    const float* bbp = bb + 640;

    u32x4 pa[2], pbv;
    #define GLOAD2(kt)                                                         \
        do {                                                                   \
            _Pragma("unroll")                                                  \
            for (int i = 0; i < 2; ++i)                                        \
                pa[i] = *(const u32x4*)&Zu[(size_t)(row0 + sm + i * 64) * WW + (kt) * 32 + sko]; \
            pbv = *(const u32x4*)&Wn[(size_t)sm * WW + (kt) * 32 + sko];       \
        } while (0)
    #define LWRITE2(buf)                                                       \
        do {                                                                   \
            _Pragma("unroll")                                                  \
            for (int i = 0; i < 2; ++i)                                        \
                *(u32x4*)&As[buf][(sm + i * 64) * KP + sko] = pa[i];           \
            *(u32x4*)&Bs[buf][sm * KP + sko] = pbv;                            \
        } while (0)

    f32x16 acc[2];
    #pragma unroll
    for (int ns = 0; ns < 2; ++ns)
        #pragma unroll
        for (int i = 0; i < 16; ++i) acc[ns][i] = 0.f;

    GLOAD2(0); LWRITE2(0);
    GLOAD2(1);

    for (int kt = 0; kt < 16; ++kt) {
        __syncthreads();
        const int buf = kt & 1;
        #pragma unroll
        for (int ks = 0; ks < 2; ++ks) {
            U4 af;
            af.u4 = *(const u32x4*)&As[buf][(wv * 32 + cc) * KP + ks * 16 + g * 8];
            #pragma unroll
            for (int ns = 0; ns < 2; ++ns) {
                U4 bf2;
                bf2.u4 = *(const u32x4*)&Bs[buf][(ns * 32 + cc) * KP + ks * 16 + g * 8];
                acc[ns] = mfma_bf16(af.v, bf2.v, acc[ns]);
            }
        }
        if (kt < 15) {
            LWRITE2(buf ^ 1);
            if (kt < 14) GLOAD2(kt + 2);
        }
    }
    #undef GLOAD2
    #undef LWRITE2

    const int fl = *flag;
    #pragma unroll
    for (int ns = 0; ns < 2; ++ns) {
        const int c = ns * 32 + cc;
        const float bias = bbp[c];
        #pragma unroll
        for (int reg = 0; reg < 16; ++reg) {
            const int r = (reg & 3) + 8 * (reg >> 2) + 4 * g;
            const int row = row0 + wv * 32 + r;
            const float v = acc[ns][reg] + bias;
            if (fl) ((float*)out)[(size_t)row * DD + c] = v;
            else    ((bf16*)out)[(size_t)row * DD + c] = __float2bfloat16(v);
        }
    }
}

// ---------------------------------------------------------------------------
extern "C" void kernel_launch(void* const* d_in, const int* in_sizes, int n_in,
                              void* d_out, int out_size, void* d_ws, size_t ws_size,
                              hipStream_t stream)
{
    const void* x  = d_in[0];
    const void* Wq = d_in[1];
    const void* bq = d_in[2];
    const void* Wk = d_in[3];
    const void* bk = d_in[4];
    const void* Wv = d_in[5];
    const void* bv = d_in[6];
    const void* Wp = d_in[7];
    const void* bp = d_in[8];

    // ws: Kb 1MB | (free) | Qb 8MB | Zb 8MB | flag+Wb+bb | Vtg 1MB | Zp (TSx16MB) | Lp
    char* ws = (char*)d_ws;
    bf16* Kb = (bf16*)(ws);
    bf16* Qb = (bf16*)(ws + (2u << 20));
    bf16* Zb = (bf16*)(ws + (10u << 20));
    int* flag = (int*)(ws + (18u << 20));
    unsigned short* Wb = (unsigned short*)(ws + (18u << 20) + 64);
    float* bb = (float*)(ws + (18u << 20) + 64 + 704 * 512 * 2);
    unsigned short* Vtg = (unsigned short*)(ws + (19u << 20));
    float* Zp = (float*)(ws + (20u << 20));

    const size_t base = (size_t)(20u << 20);
    const size_t need4 = base + 4 * ZP_PART * 4 + 4 * LP_PART * 4;
    const size_t need2 = base + 2 * ZP_PART * 4 + 2 * LP_PART * 4;

    wprep_kernel<<<88, 256, 0, stream>>>(x, Wq, bq, Wk, bk, Wv, bv, Wp, bp, Wb, bb, flag);
    proj_mfma_kernel<<<320, 256, 0, stream>>>(x, Wb, bb, Kb, Qb, Vtg);

    if (ws_size >= need4) {
        float* Lp = (float*)(ws + base + 4 * ZP_PART * 4);
        attn_mfma_kernel<4><<<16 * 32 * 4, 256, 0, stream>>>(Kb, Vtg, Qb, Zb, Zp, Lp);
        combine_kernel<4><<<2048, 256, 0, stream>>>(Zp, Lp, Zb);
    } else if (ws_size >= need2) {
        float* Lp = (float*)(ws + base + 2 * ZP_PART * 4);
        attn_mfma_kernel<2><<<16 * 32 * 2, 256, 0, stream>>>(Kb, Vtg, Qb, Zb, Zp, Lp);
        combine_kernel<2><<<2048, 256, 0, stream>>>(Zp, Lp, Zb);
    } else {
        float* Lp = (float*)(ws + base);
        attn_mfma_kernel<1><<<16 * 32, 256, 0, stream>>>(Kb, Vtg, Qb, Zb, Zp, Lp);
    }
    outp_mfma_kernel<<<64, 256, 0, stream>>>(Zb, Wb, bb, flag, d_out);
}